// Round 15
// baseline (231.313 us; speedup 1.0000x reference)
//
#include <hip/hip_runtime.h>

typedef __attribute__((ext_vector_type(8))) short short8;
typedef __attribute__((ext_vector_type(4))) float floatx4;
typedef __attribute__((ext_vector_type(2))) float floatx2;

// ---------------- constants ----------------
#define FH 96
#define FW 312
#define FC 256
#define NP 25281
#define NPR 25344          // NP rounded to 64
#define NCELL 7
#define KDIM 1792

__device__ __forceinline__ unsigned short f2bf(float x) {
    union { float f; unsigned u; } v; v.f = x;
    return (unsigned short)((v.u + 0x7fffu + ((v.u >> 16) & 1u)) >> 16);
}
__device__ __forceinline__ float clip1(float v) { return fminf(fmaxf(v, -1.f), 1.f); }
__device__ __forceinline__ int   rfl (int x)   { return __builtin_amdgcn_readfirstlane(x); }
__device__ __forceinline__ float rflf(float x) { return __int_as_float(__builtin_amdgcn_readfirstlane(__float_as_int(x))); }

struct __attribute__((packed, aligned(4))) f4u { float x, y, z, w; };

// ---------------- K1 fused: x-cumsum+transpose (blocks 0..767) | prep tables (768..1039) ----------------
__global__ __launch_bounds__(256) void k_xscanT(const float* __restrict__ f, float* __restrict__ iit,
                       const float* __restrict__ W, unsigned short* __restrict__ B2,
                       int4* __restrict__ XTc, float4* __restrict__ XTw,
                       float* __restrict__ YRt, int* __restrict__ Rd,
                       int4* __restrict__ YTc, float4* __restrict__ YTw) {
    __shared__ float sl[32][313];
    const int tid = threadIdx.x, lane = tid & 63, wv = tid >> 6;
    if (blockIdx.x < 768) {
        const int y = blockIdx.x % 96, cb = (blockIdx.x / 96) * 32;
        float v[8][5];
#pragma unroll
        for (int cri = 0; cri < 8; ++cri) {
            const float* src = f + (size_t)(cb + wv * 8 + cri) * (FH * FW) + y * FW;
#pragma unroll
            for (int s = 0; s < 5; ++s) {
                const int x = s * 64 + lane;
                v[cri][s] = (x < FW) ? src[x] : 0.f;
            }
        }
        // 40 independent intra-segment scans (6-deep shfl chains, fully interleaved)
#pragma unroll
        for (int d = 1; d < 64; d <<= 1) {
#pragma unroll
            for (int cri = 0; cri < 8; ++cri)
#pragma unroll
                for (int s = 0; s < 5; ++s) {
                    const float up = __shfl_up(v[cri][s], d, 64);
                    if (lane >= d) v[cri][s] += up;
                }
        }
        // combine segments via wave-uniform totals
#pragma unroll
        for (int cri = 0; cri < 8; ++cri) {
            const float t0 = __shfl(v[cri][0], 63, 64);
            const float t1 = __shfl(v[cri][1], 63, 64);
            const float t2 = __shfl(v[cri][2], 63, 64);
            const float t3 = __shfl(v[cri][3], 63, 64);
            const float o1 = t0, o2 = o1 + t1, o3 = o2 + t2, o4 = o3 + t3;
            v[cri][1] += o1; v[cri][2] += o2; v[cri][3] += o3; v[cri][4] += o4;
        }
#pragma unroll
        for (int cri = 0; cri < 8; ++cri) {
            const int cr = wv * 8 + cri;
#pragma unroll
            for (int s = 0; s < 5; ++s) {
                const int x = s * 64 + lane;
                if (x < FW) sl[cr][x] = v[cri][s];
            }
        }
        __syncthreads();
        const int cw = lane & 31, xo = lane >> 5;
        for (int xi = wv * 2; xi < FW; xi += 8) {
            const int xx = xi + xo;
            iit[(size_t)(y * FW + xx) * FC + cb + cw] = sl[cw][xx];
        }
        return;
    }
    const int b = blockIdx.x - 768;
    const float step = 80.f / 159.f;
    if (b < 99) {
        // X tap table per p, invx folded into weights
        const int p = b * 256 + tid;
        if (p < NP) {
            const int d = p / 159, w = p - d * 159;
            const float z0 = 1.f + d * step, z1 = z0 + step;
            const float xa = -40.f + w * step, xb = xa + step;
            const float n00 = clip1((1000.f * xa + 1248.f * z0) / z0 * (2.f / 2496.f) - 1.f);
            const float n10 = clip1((1000.f * xa + 1248.f * z1) / z1 * (2.f / 2496.f) - 1.f);
            const float n01 = clip1((1000.f * xb + 1248.f * z0) / z0 * (2.f / 2496.f) - 1.f);
            const float n11 = clip1((1000.f * xb + 1248.f * z1) / z1 * (2.f / 2496.f) - 1.f);
            const float xmin = fminf(n00, n10);
            const float xmax = fmaxf(n11, n01);
            const float pa = (xmin + 1.f) * (0.5f * FW) - 0.5f;
            const float pb = (xmax + 1.f) * (0.5f * FW) - 0.5f;
            const float fa = floorf(pa), fb = floorf(pb);
            const float wa = pa - fa, wb = pb - fb;
            const int a0 = (int)fa, b0 = (int)fb;
            const float xd = xmax - xmin;
            const float invx = (xd > 0.f) ? (1.f / xd) : 0.f;
            int   cc[4] = { a0, a0 + 1, b0, b0 + 1 };
            float ww[4] = { -(1.f - wa), -wa, (1.f - wb), wb };
#pragma unroll
            for (int i = 0; i < 4; ++i) {
                if (cc[i] < 0 || cc[i] >= FW) { cc[i] = 0; ww[i] = 0.f; }
                ww[i] *= invx;
            }
            XTc[p] = make_int4(cc[0], cc[1], cc[2], cc[3]);
            XTw[p] = make_float4(ww[0], ww[1], ww[2], ww[3]);
        }
    } else if (b < 139) {
        // per-d deduplicated + group-4-padded y-row tables; one wave per d
        const int d = (b - 99) * 4 + wv;
        if (d < 159) {
            const int t = lane;
            const int kcell = (t >> 2) & 7;
            const int tap = t & 3;
            const float z0 = 1.f + d * step, z1 = z0 + step;
            const float ya = -2.f + 0.5f * kcell, yb2 = ya + 0.5f;
            const float m0 = clip1((1000.f * ya  + 384.f * z0) / z0 * (2.f / 768.f) - 1.f);
            const float m1 = clip1((1000.f * ya  + 384.f * z1) / z1 * (2.f / 768.f) - 1.f);
            const float M0 = clip1((1000.f * yb2 + 384.f * z0) / z0 * (2.f / 768.f) - 1.f);
            const float M1 = clip1((1000.f * yb2 + 384.f * z1) / z1 * (2.f / 768.f) - 1.f);
            const float ymin = fminf(m0, m1);
            const float ymax = fmaxf(M0, M1);
            const float yd = ymax - ymin;
            const float invy = (yd > 0.f) ? (1.f / (yd * (FH * FW * 0.25f))) : 0.f;
            const float pa = (ymin + 1.f) * (0.5f * FH) - 0.5f;
            const float pb = (ymax + 1.f) * (0.5f * FH) - 0.5f;
            const float fa = floorf(pa), fb = floorf(pb);
            const float wa = pa - fa, wb = pb - fb;
            int row; float w;
            if      (tap == 0) { row = (int)fa;     w = -(1.f - wa); }
            else if (tap == 1) { row = (int)fa + 1; w = -wa; }
            else if (tap == 2) { row = (int)fb;     w =  (1.f - wb); }
            else               { row = (int)fb + 1; w =  wb; }
            w *= invy;
            const bool valid = (t < 28) && (row >= 0) && (row < FH) && (w != 0.f);
            if (!valid) { row = 0; w = 0.f; }
            int first = 63;
#pragma unroll
            for (int j = 0; j < 28; ++j) {
                const int rj = __shfl(row, j, 64);
                if (rj == row && j < first) first = j;
            }
            const bool leader = (t < 28) && (first == t);
            const unsigned long long mask = __ballot(leader);
            const int slot = (int)__popcll(mask & ((1ull << t) - 1ull));
            const int Rn = (int)__popcll(mask);
            const int ng = (Rn + 3) >> 2;
            float s0 = 0.f, s1 = 0.f, s2 = 0.f, s3 = 0.f, s4 = 0.f, s5 = 0.f, s6 = 0.f;
#pragma unroll
            for (int j = 0; j < 28; ++j) {
                const int rj = __shfl(row, j, 64);
                const float wj = __shfl(w, j, 64);
                const float add = (rj == row) ? wj : 0.f;
                const int kj = j >> 2;
                if      (kj == 0) s0 += add;
                else if (kj == 1) s1 += add;
                else if (kj == 2) s2 += add;
                else if (kj == 3) s3 += add;
                else if (kj == 4) s4 += add;
                else if (kj == 5) s5 += add;
                else              s6 += add;
            }
            if (leader) {
                float* rec = YRt + ((size_t)d * 28 + slot) * 8;
                rec[0] = s0; rec[1] = s1; rec[2] = s2; rec[3] = s3;
                rec[4] = s4; rec[5] = s5; rec[6] = s6;
                ((int*)rec)[7] = 0;  // row written below as int
                ((int*)rec)[7] = row;
            }
            if ((t >= Rn) && (t < ng * 4)) {           // zero-pad to full groups
                float* rec = YRt + ((size_t)d * 28 + t) * 8;
                rec[0] = 0.f; rec[1] = 0.f; rec[2] = 0.f; rec[3] = 0.f;
                rec[4] = 0.f; rec[5] = 0.f; rec[6] = 0.f;
                ((int*)rec)[7] = 0;
            }
            if (t == 0) Rd[d] = ng;
        }
    } else if (b < 144) {
        // fallback per-(d,kc) y tables (folded weights) — only used on the C path
        const int p = (b - 139) * 256 + tid;
        if (p < 159 * NCELL) {
            const int d = p / NCELL, k = p - (p / NCELL) * NCELL;
            const float z0 = 1.f + d * step, z1 = z0 + step;
            const float ya = -2.f + 0.5f * k, yb2 = ya + 0.5f;
            const float m0 = clip1((1000.f * ya  + 384.f * z0) / z0 * (2.f / 768.f) - 1.f);
            const float m1 = clip1((1000.f * ya  + 384.f * z1) / z1 * (2.f / 768.f) - 1.f);
            const float M0 = clip1((1000.f * yb2 + 384.f * z0) / z0 * (2.f / 768.f) - 1.f);
            const float M1 = clip1((1000.f * yb2 + 384.f * z1) / z1 * (2.f / 768.f) - 1.f);
            const float ymin = fminf(m0, m1);
            const float ymax = fmaxf(M0, M1);
            const float yd = ymax - ymin;
            const float invy = (yd > 0.f) ? (1.f / (yd * (FH * FW * 0.25f))) : 0.f;
            const float pa = (ymin + 1.f) * (0.5f * FH) - 0.5f;
            const float pb = (ymax + 1.f) * (0.5f * FH) - 0.5f;
            const float fa = floorf(pa), fb = floorf(pb);
            const float wa = pa - fa, wb = pb - fb;
            const int a0 = (int)fa, b0 = (int)fb;
            int   rr[4] = { a0, a0 + 1, b0, b0 + 1 };
            float rw[4] = { -(1.f - wa), -wa, (1.f - wb), wb };
#pragma unroll
            for (int i = 0; i < 4; ++i) {
                if (rr[i] < 0 || rr[i] >= FH) { rr[i] = 0; rw[i] = 0.f; }
                rw[i] *= invy;
            }
            YTc[p] = make_int4(rr[0], rr[1], rr[2], rr[3]);
            YTw[p] = make_float4(rw[0], rw[1], rw[2], rw[3]);
        }
    } else {
        // LDS-staged B2 repack (sw overlays sl). Block -> (ks, nt).
        float (*sw)[224] = (float(*)[224])&sl[0][0];
        const int bb = b - 144;               // 0..127
        const int ks = bb >> 4, nt2 = bb & 15;
        for (int idx = tid; idx < 3584; idx += 256) {
            const int n = idx / 224, off = idx - n * 224;
            sw[n][off] = W[(size_t)(nt2 * 16 + n) * KDIM + ks * 224 + off];
        }
        __syncthreads();
        for (int ee = tid; ee < 3584; ee += 256) {
            const int kc = ee >> 9, ln = (ee >> 3) & 63, j = ee & 7;
            const int nl = ln & 15, cl = ((ln >> 4) & 3) * 8 + j;
            B2[(size_t)kc * 65536 + ks * 8192 + nt2 * 512 + ln * 8 + j] = f2bf(sw[nl][cl * 7 + kc]);
        }
    }
}

// ---------------- K1b: y-cumsum, y split into two 48-halves (2x waves, half the chain) ----------------
__global__ __launch_bounds__(256) void k_ysum(float* __restrict__ iit) {
    __shared__ float tot[128];
    const int x = blockIdx.x;
    const int cl = threadIdx.x & 127;
    const int hf = threadIdx.x >> 7;
    const int c = blockIdx.y * 128 + cl;
    float* base = iit + (size_t)x * FC + c + (size_t)(hf * 48) * (FW * FC);
    float v[48];
#pragma unroll
    for (int y = 0; y < 48; ++y) v[y] = base[(size_t)y * (FW * FC)];
    float s = 0.f;
#pragma unroll
    for (int y = 0; y < 48; ++y) { s += v[y]; v[y] = s; }
    if (hf == 0) tot[cl] = s;
    __syncthreads();
    const float off = (hf == 1) ? tot[cl] : 0.f;
#pragma unroll
    for (int y = 0; y < 48; ++y) base[(size_t)y * (FW * FC)] = v[y] + off;
}

// ---------------- K3a: dedup gather -> vox[p][kc*256+c] (bf16), one wave per p ----------------
// Frozen algorithm (memory-bound). DIAGNOSTIC: two balanced half-dispatches by
// strip-OCTET parity (hoff 0 / 8): each half samples the full depth range, so per-half
// ng-work stays balanced; each half ~42us < k_mm so the top-5 exposes k_mm's duration.
__global__ __launch_bounds__(256, 4) void k_gather(
    const float* __restrict__ iit,
    const int4* __restrict__ XTc, const float4* __restrict__ XTw,
    const float* __restrict__ YRt, const int* __restrict__ Rd,
    unsigned short* __restrict__ vox, int hoff)
{
    const int tid = threadIdx.x, lane = tid & 63, wv = tid >> 6;
    const int b = blockIdx.x;
    const int j  = b >> 3;                            // 0..395
    const int strip = (b & 7) + (j / 99) * 16 + hoff; // octets {0,2,4,6}+hoff/8
    const int L = strip * 99 + (j % 99);
    const int p = L * 4 + wv;
    if (p >= NP) return;                       // wave-uniform
    const int4  xc = XTc[p];
    const float4 xw = XTw[p];
    const int dd = p / 159;
    const int ng = rfl(Rd[dd]);
    const float* yt = YRt + (size_t)dd * 224;
    // lane j (<28) holds the dedup'd row index of slot j for this depth
    int rowv = 0;
    if (lane < 28) rowv = ((const int*)yt)[lane * 8 + 7];
    const int c0 = rfl(xc.x), c1 = rfl(xc.y), c2 = rfl(xc.z), c3 = rfl(xc.w);
    const float wx0 = rflf(xw.x), wx1 = rflf(xw.y), wx2 = rflf(xw.z), wx3 = rflf(xw.w);
    const int lo = lane * 4;                    // shared per-lane offset (floats)
    const int u0 = c0 * FC, u1 = c1 * FC, u2 = c2 * FC, u3 = c3 * FC;  // uniform col offsets

    floatx2 a0a = {0.f,0.f}, a0b = a0a, a1a = a0a, a1b = a0a, a2a = a0a, a2b = a0a,
            a3a = a0a, a3b = a0a, a4a = a0a, a4b = a0a, a5a = a0a, a5b = a0a,
            a6a = a0a, a6b = a0a;

#define LO2(T) ((floatx2){T.x, T.y})
#define HI2(T) ((floatx2){T.z, T.w})

#pragma unroll 2
    for (int g = 0; g < ng; ++g) {
        // rows via readlane -> SGPR; all address math below is wave-uniform (SALU)
        const int r0 = __builtin_amdgcn_readlane(rowv, 4 * g + 0);
        const int r1 = __builtin_amdgcn_readlane(rowv, 4 * g + 1);
        const int r2 = __builtin_amdgcn_readlane(rowv, 4 * g + 2);
        const int r3 = __builtin_amdgcn_readlane(rowv, 4 * g + 3);
        const float* R0 = iit + (size_t)(r0 * (FW * FC));
        const float* R1 = iit + (size_t)(r1 * (FW * FC));
        const float* R2 = iit + (size_t)(r2 * (FW * FC));
        const float* R3 = iit + (size_t)(r3 * (FW * FC));
        const float* B00 = R0 + u0; const float* B01 = R0 + u1; const float* B02 = R0 + u2; const float* B03 = R0 + u3;
        const float* B10 = R1 + u0; const float* B11 = R1 + u1; const float* B12 = R1 + u2; const float* B13 = R1 + u3;
        const float* B20 = R2 + u0; const float* B21 = R2 + u1; const float* B22 = R2 + u2; const float* B23 = R2 + u3;
        const float* B30 = R3 + u0; const float* B31 = R3 + u1; const float* B32 = R3 + u2; const float* B33 = R3 + u3;
        const float4 t00 = *(const float4*)(B00 + lo);
        const float4 t01 = *(const float4*)(B01 + lo);
        const float4 t02 = *(const float4*)(B02 + lo);
        const float4 t03 = *(const float4*)(B03 + lo);
        const float4 t10 = *(const float4*)(B10 + lo);
        const float4 t11 = *(const float4*)(B11 + lo);
        const float4 t12 = *(const float4*)(B12 + lo);
        const float4 t13 = *(const float4*)(B13 + lo);
        const float4 t20 = *(const float4*)(B20 + lo);
        const float4 t21 = *(const float4*)(B21 + lo);
        const float4 t22 = *(const float4*)(B22 + lo);
        const float4 t23 = *(const float4*)(B23 + lo);
        const float4 t30 = *(const float4*)(B30 + lo);
        const float4 t31 = *(const float4*)(B31 + lo);
        const float4 t32 = *(const float4*)(B32 + lo);
        const float4 t33 = *(const float4*)(B33 + lo);
        const float* tp = yt + g * 32;
        const float4 wa0 = *(const float4*)(tp +  0), wb0 = *(const float4*)(tp +  4);
        const float4 wa1 = *(const float4*)(tp +  8), wb1 = *(const float4*)(tp + 12);
        const float4 wa2 = *(const float4*)(tp + 16), wb2 = *(const float4*)(tp + 20);
        const float4 wa3 = *(const float4*)(tp + 24), wb3 = *(const float4*)(tp + 28);
        // x-combine on packed float2 halves (v_pk_fma_f32)
        const floatx2 U0a = LO2(t00)*wx0 + LO2(t01)*wx1 + LO2(t02)*wx2 + LO2(t03)*wx3;
        const floatx2 U0b = HI2(t00)*wx0 + HI2(t01)*wx1 + HI2(t02)*wx2 + HI2(t03)*wx3;
        const floatx2 U1a = LO2(t10)*wx0 + LO2(t11)*wx1 + LO2(t12)*wx2 + LO2(t13)*wx3;
        const floatx2 U1b = HI2(t10)*wx0 + HI2(t11)*wx1 + HI2(t12)*wx2 + HI2(t13)*wx3;
        const floatx2 U2a = LO2(t20)*wx0 + LO2(t21)*wx1 + LO2(t22)*wx2 + LO2(t23)*wx3;
        const floatx2 U2b = HI2(t20)*wx0 + HI2(t21)*wx1 + HI2(t22)*wx2 + HI2(t23)*wx3;
        const floatx2 U3a = LO2(t30)*wx0 + LO2(t31)*wx1 + LO2(t32)*wx2 + LO2(t33)*wx3;
        const floatx2 U3b = HI2(t30)*wx0 + HI2(t31)*wx1 + HI2(t32)*wx2 + HI2(t33)*wx3;
        // y-accumulate per cell, packed
#define SC2(Aa, Ab, W0, W1, W2, W3) { \
        Aa += U0a*(W0) + U1a*(W1) + U2a*(W2) + U3a*(W3); \
        Ab += U0b*(W0) + U1b*(W1) + U2b*(W2) + U3b*(W3); }
        SC2(a0a, a0b, wa0.x, wa1.x, wa2.x, wa3.x)
        SC2(a1a, a1b, wa0.y, wa1.y, wa2.y, wa3.y)
        SC2(a2a, a2b, wa0.z, wa1.z, wa2.z, wa3.z)
        SC2(a3a, a3b, wa0.w, wa1.w, wa2.w, wa3.w)
        SC2(a4a, a4b, wb0.x, wb1.x, wb2.x, wb3.x)
        SC2(a5a, a5b, wb0.y, wb1.y, wb2.y, wb3.y)
        SC2(a6a, a6b, wb0.z, wb1.z, wb2.z, wb3.z)
#undef SC2
    }
#undef LO2
#undef HI2

    unsigned short* vp = vox + (size_t)p * KDIM;
#define PK2(Aa, Ab) make_uint2((unsigned)f2bf(Aa.x) | ((unsigned)f2bf(Aa.y) << 16), \
                               (unsigned)f2bf(Ab.x) | ((unsigned)f2bf(Ab.y) << 16))
    *(uint2*)(vp + 0 * 256 + lo) = PK2(a0a, a0b);
    *(uint2*)(vp + 1 * 256 + lo) = PK2(a1a, a1b);
    *(uint2*)(vp + 2 * 256 + lo) = PK2(a2a, a2b);
    *(uint2*)(vp + 3 * 256 + lo) = PK2(a3a, a3b);
    *(uint2*)(vp + 4 * 256 + lo) = PK2(a4a, a4b);
    *(uint2*)(vp + 5 * 256 + lo) = PK2(a5a, a5b);
    *(uint2*)(vp + 6 * 256 + lo) = PK2(a6a, a6b);
#undef PK2
}

// ---------------- K3b: GEMM vox(bf16) x B2 -> out, M-tile 64, 8 waves (R11 config, best) ----------------
__global__ __launch_bounds__(512, 4) void k_mm(
    const unsigned short* __restrict__ vox, const unsigned short* __restrict__ B2,
    const float* __restrict__ bias, float* __restrict__ out)
{
    __shared__ unsigned short As[64][268];
    const int tid = threadIdx.x, lane = tid & 63, wv = tid >> 6;  // wv 0..7
    const int b = blockIdx.x;
    const int L = (b & 7) * 50 + (b >> 3);   // 400 = 8 x 50
    const int p0 = L * 64;
    const int q = lane >> 4, r = lane & 15;

    floatx4 acc[4][2];
#pragma unroll
    for (int mt = 0; mt < 4; ++mt)
#pragma unroll
        for (int nt = 0; nt < 2; ++nt) acc[mt][nt] = (floatx4){0.f, 0.f, 0.f, 0.f};

    const int srow = tid >> 5, scol = (tid & 31) * 8;  // srow 0..15
    for (int kk = 0; kk < 7; ++kk) {
        // stage 64 x 256 bf16 chunk of vox (512 threads: 4 rows of 16)
#pragma unroll
        for (int r8 = 0; r8 < 4; ++r8) {
            const int row = r8 * 16 + srow;
            int pg = p0 + row; if (pg > NPR - 1) pg = NPR - 1;
            const float4 v = *(const float4*)(vox + (size_t)pg * KDIM + kk * 256 + scol);
            *(float4*)&As[row][scol] = v;
        }
        __syncthreads();
#pragma unroll
        for (int ks = 0; ks < 8; ++ks) {
            short8 af[4], bf[2];
#pragma unroll
            for (int mt = 0; mt < 4; ++mt)
                af[mt] = *(const short8*)&As[mt * 16 + r][ks * 32 + q * 8];
#pragma unroll
            for (int nt = 0; nt < 2; ++nt)
                bf[nt] = *(const short8*)(B2 + (size_t)((((kk * 8 + ks) * 16) + (wv * 2 + nt)) * 64 + lane) * 8);
#pragma unroll
            for (int mt = 0; mt < 4; ++mt)
#pragma unroll
                for (int nt = 0; nt < 2; ++nt)
                    acc[mt][nt] = __builtin_amdgcn_mfma_f32_16x16x32_bf16(af[mt], bf[nt], acc[mt][nt], 0, 0, 0);
        }
        __syncthreads();
    }

#pragma unroll
    for (int nt = 0; nt < 2; ++nt) {
        const int co = wv * 32 + nt * 16 + r;
        const float bs = bias[co];
#pragma unroll
        for (int mt = 0; mt < 4; ++mt) {
            const int pb = p0 + mt * 16 + q * 4;
            float* op = out + (size_t)co * NP + pb;
            if (pb + 4 <= NP) {
                f4u vv;
                vv.x = fmaxf(acc[mt][nt][0] + bs, 0.f);
                vv.y = fmaxf(acc[mt][nt][1] + bs, 0.f);
                vv.z = fmaxf(acc[mt][nt][2] + bs, 0.f);
                vv.w = fmaxf(acc[mt][nt][3] + bs, 0.f);
                *(f4u*)op = vv;
            } else {
#pragma unroll
                for (int e2 = 0; e2 < 4; ++e2)
                    if (pb + e2 < NP) op[e2] = fmaxf(acc[mt][nt][e2] + bs, 0.f);
            }
        }
    }
}

// ---------------- fallback fused kernel (R4 lineage, folded weights) ----------------
__device__ __forceinline__ float4 gather_row_fb(
    const float* __restrict__ iit, int lane,
    const int4* __restrict__ XTc, const float4* __restrict__ XTw,
    const int4* __restrict__ YTc, const float4* __restrict__ YTw,
    int p, int kc)
{
    const int pl = (p < NP) ? p : (NP - 1);
    const int4  xc = XTc[pl];
    const float4 xw = XTw[pl];
    const int dd = (int)((unsigned)pl / 159u);
    const int4  yc = YTc[dd * NCELL + kc];
    const float4 yw = YTw[dd * NCELL + kc];
    const int r0 = rfl(yc.x), r1 = rfl(yc.y), r2 = rfl(yc.z), r3 = rfl(yc.w);
    const int c0 = rfl(xc.x), c1 = rfl(xc.y), c2 = rfl(xc.z), c3 = rfl(xc.w);
    const float keep = (p < NP) ? 1.f : 0.f;
    const float wy0 = rflf(yw.x) * keep, wy1 = rflf(yw.y) * keep, wy2 = rflf(yw.z) * keep, wy3 = rflf(yw.w) * keep;
    const float wx0 = rflf(xw.x), wx1 = rflf(xw.y), wx2 = rflf(xw.z), wx3 = rflf(xw.w);
    const int lo = lane * 4;
    const float* q00 = iit + (size_t)(r0 * FW + c0) * FC + lo;
    const float* q01 = iit + (size_t)(r0 * FW + c1) * FC + lo;
    const float* q02 = iit + (size_t)(r0 * FW + c2) * FC + lo;
    const float* q03 = iit + (size_t)(r0 * FW + c3) * FC + lo;
    const float* q10 = iit + (size_t)(r1 * FW + c0) * FC + lo;
    const float* q11 = iit + (size_t)(r1 * FW + c1) * FC + lo;
    const float* q12 = iit + (size_t)(r1 * FW + c2) * FC + lo;
    const float* q13 = iit + (size_t)(r1 * FW + c3) * FC + lo;
    const float* q20 = iit + (size_t)(r2 * FW + c0) * FC + lo;
    const float* q21 = iit + (size_t)(r2 * FW + c1) * FC + lo;
    const float* q22 = iit + (size_t)(r2 * FW + c2) * FC + lo;
    const float* q23 = iit + (size_t)(r2 * FW + c3) * FC + lo;
    const float* q30 = iit + (size_t)(r3 * FW + c0) * FC + lo;
    const float* q31 = iit + (size_t)(r3 * FW + c1) * FC + lo;
    const float* q32 = iit + (size_t)(r3 * FW + c2) * FC + lo;
    const float* q33 = iit + (size_t)(r3 * FW + c3) * FC + lo;
    const float4 t00 = *(const float4*)q00;
    const float4 t01 = *(const float4*)q01;
    const float4 t02 = *(const float4*)q02;
    const float4 t03 = *(const float4*)q03;
    const float4 t10 = *(const float4*)q10;
    const float4 t11 = *(const float4*)q11;
    const float4 t12 = *(const float4*)q12;
    const float4 t13 = *(const float4*)q13;
    const float4 t20 = *(const float4*)q20;
    const float4 t21 = *(const float4*)q21;
    const float4 t22 = *(const float4*)q22;
    const float4 t23 = *(const float4*)q23;
    const float4 t30 = *(const float4*)q30;
    const float4 t31 = *(const float4*)q31;
    const float4 t32 = *(const float4*)q32;
    const float4 t33 = *(const float4*)q33;
    float4 a = make_float4(0.f, 0.f, 0.f, 0.f);
#define ACC(T, WY, WX) { const float wt = (WY) * (WX); \
        a.x += wt * T.x; a.y += wt * T.y; a.z += wt * T.z; a.w += wt * T.w; }
    ACC(t00, wy0, wx0) ACC(t01, wy0, wx1) ACC(t02, wy0, wx2) ACC(t03, wy0, wx3)
    ACC(t10, wy1, wx0) ACC(t11, wy1, wx1) ACC(t12, wy1, wx2) ACC(t13, wy1, wx3)
    ACC(t20, wy2, wx0) ACC(t21, wy2, wx1) ACC(t22, wy2, wx2) ACC(t23, wy2, wx3)
    ACC(t30, wy3, wx0) ACC(t31, wy3, wx1) ACC(t32, wy3, wx2) ACC(t33, wy3, wx3)
#undef ACC
    return a;
}

__global__ __launch_bounds__(256, 4) void k_fusedC(
    const float* __restrict__ iit, const unsigned short* __restrict__ B2,
    const int4* __restrict__ XTc, const float4* __restrict__ XTw,
    const int4* __restrict__ YTc, const float4* __restrict__ YTw,
    const float* __restrict__ bias, float* __restrict__ out)
{
    __shared__ unsigned short As[32][264];
    const int tid = threadIdx.x, lane = tid & 63, wv = tid >> 6;
    const int b = blockIdx.x;
    const int L = (b & 7) * 99 + (b >> 3);
    const int p0 = L * 32;
    const int q = lane >> 4, r = lane & 15;

    floatx4 acc[2][4];
#pragma unroll
    for (int mt = 0; mt < 2; ++mt)
#pragma unroll
        for (int nt = 0; nt < 4; ++nt) acc[mt][nt] = (floatx4){0.f, 0.f, 0.f, 0.f};

    for (int kc = 0; kc < NCELL; ++kc) {
#pragma unroll 1
        for (int i = 0; i < 8; ++i) {
            const int pr = wv * 8 + i;
            const float4 a = gather_row_fb(iit, lane, XTc, XTw, YTc, YTw, p0 + pr, kc);
            *(uint2*)&As[pr][lane * 4] = make_uint2(
                (unsigned)f2bf(a.x) | ((unsigned)f2bf(a.y) << 16),
                (unsigned)f2bf(a.z) | ((unsigned)f2bf(a.w) << 16));
        }
        __syncthreads();
#pragma unroll
        for (int ks = 0; ks < 8; ++ks) {
            short8 af[2], bf[4];
#pragma unroll
            for (int mt = 0; mt < 2; ++mt)
                af[mt] = *(const short8*)&As[mt * 16 + r][ks * 32 + q * 8];
#pragma unroll
            for (int nt = 0; nt < 4; ++nt)
                bf[nt] = *(const short8*)(B2 + (size_t)((((kc * 8 + ks) * 16) + (wv * 4 + nt)) * 64 + lane) * 8);
#pragma unroll
            for (int mt = 0; mt < 2; ++mt)
#pragma unroll
                for (int nt = 0; nt < 4; ++nt)
                    acc[mt][nt] = __builtin_amdgcn_mfma_f32_16x16x32_bf16(af[mt], bf[nt], acc[mt][nt], 0, 0, 0);
        }
        __syncthreads();
    }

#pragma unroll
    for (int nt = 0; nt < 4; ++nt) {
        const int co = wv * 64 + nt * 16 + r;
        const float bs = bias[co];
#pragma unroll
        for (int mt = 0; mt < 2; ++mt) {
            const int pb = p0 + mt * 16 + q * 4;
            float* op = out + (size_t)co * NP + pb;
            if (pb + 4 <= NP) {
                f4u vv;
                vv.x = fmaxf(acc[mt][nt][0] + bs, 0.f);
                vv.y = fmaxf(acc[mt][nt][1] + bs, 0.f);
                vv.z = fmaxf(acc[mt][nt][2] + bs, 0.f);
                vv.w = fmaxf(acc[mt][nt][3] + bs, 0.f);
                *(f4u*)op = vv;
            } else {
#pragma unroll
                for (int e2 = 0; e2 < 4; ++e2)
                    if (pb + e2 < NP) op[e2] = fmaxf(acc[mt][nt][e2] + bs, 0.f);
            }
        }
    }
}

// ---------------- launch ----------------
extern "C" void kernel_launch(void* const* d_in, const int* in_sizes, int n_in,
                              void* d_out, int out_size, void* d_ws, size_t ws_size,
                              hipStream_t stream) {
    (void)in_sizes; (void)n_in; (void)out_size;
    const float* features = (const float*)d_in[0];
    const float* W_lin    = (const float*)d_in[4];
    const float* b_lin    = (const float*)d_in[5];
    float* out = (float*)d_out;
    char* ws = (char*)d_ws;

    float*          iit = (float*)(ws + 0);                 // 30,670,848
    unsigned short* B2  = (unsigned short*)(ws + 30670848); //    917,504 -> 31,588,352
    int4*   XTc = (int4*)  (ws + 31588352);                 //    405,504 -> 31,993,856
    float4* XTw = (float4*)(ws + 31993856);                 //    405,504 -> 32,399,360
    float*  YRt = (float*) (ws + 32399360);                 //    142,464 -> 32,541,824
    int*    Rd  = (int*)   (ws + 32541824);                 //        640 -> 32,542,464
    int4*   YTc = (int4*)  (ws + 32542464);                 //     17,920 -> 32,560,384
    float4* YTw = (float4*)(ws + 32560384);                 //     17,920 -> 32,578,304
    unsigned short* vox = (unsigned short*)(ws + 32578304); // 90,832,896 -> 123,411,200

    k_xscanT<<<1040, 256, 0, stream>>>(features, iit, W_lin, B2, XTc, XTw, YRt, Rd, YTc, YTw);
    k_ysum  <<<dim3(312, 2), 256, 0, stream>>>(iit);

    if (ws_size >= 123411200ull) {
        k_gather<<<3168, 256, 0, stream>>>(iit, XTc, XTw, YRt, Rd, vox, 0);
        k_gather<<<3168, 256, 0, stream>>>(iit, XTc, XTw, YRt, Rd, vox, 8);
        k_mm    <<<400, 512, 0, stream>>>(vox, B2, b_lin, out);
    } else {
        k_fusedC<<<792, 256, 0, stream>>>(iit, B2, XTc, XTw, YTc, YTw, b_lin, out);
    }
}

// Round 16
// 221.985 us; speedup vs baseline: 1.0420x; 1.0420x over previous
//
#include <hip/hip_runtime.h>

typedef __attribute__((ext_vector_type(8))) short short8;
typedef __attribute__((ext_vector_type(4))) float floatx4;
typedef __attribute__((ext_vector_type(2))) float floatx2;

// ---------------- constants ----------------
#define FH 96
#define FW 312
#define FC 256
#define NP 25281
#define NPR 25344          // NP rounded to 64
#define NCELL 7
#define KDIM 1792

__device__ __forceinline__ unsigned short f2bf(float x) {
    union { float f; unsigned u; } v; v.f = x;
    return (unsigned short)((v.u + 0x7fffu + ((v.u >> 16) & 1u)) >> 16);
}
__device__ __forceinline__ float clip1(float v) { return fminf(fmaxf(v, -1.f), 1.f); }
__device__ __forceinline__ int   rfl (int x)   { return __builtin_amdgcn_readfirstlane(x); }
__device__ __forceinline__ float rflf(float x) { return __int_as_float(__builtin_amdgcn_readfirstlane(__float_as_int(x))); }

struct __attribute__((packed, aligned(4))) f4u { float x, y, z, w; };

// ---------------- K1 fused: x-cumsum+transpose (blocks 0..767) | prep tables (768..1039) ----------------
__global__ __launch_bounds__(256) void k_xscanT(const float* __restrict__ f, float* __restrict__ iit,
                       const float* __restrict__ W, unsigned short* __restrict__ B2,
                       int4* __restrict__ XTc, float4* __restrict__ XTw,
                       float* __restrict__ YRt, int* __restrict__ Rd,
                       int4* __restrict__ YTc, float4* __restrict__ YTw) {
    __shared__ float sl[32][313];
    const int tid = threadIdx.x, lane = tid & 63, wv = tid >> 6;
    if (blockIdx.x < 768) {
        const int y = blockIdx.x % 96, cb = (blockIdx.x / 96) * 32;
        float v[8][5];
#pragma unroll
        for (int cri = 0; cri < 8; ++cri) {
            const float* src = f + (size_t)(cb + wv * 8 + cri) * (FH * FW) + y * FW;
#pragma unroll
            for (int s = 0; s < 5; ++s) {
                const int x = s * 64 + lane;
                v[cri][s] = (x < FW) ? src[x] : 0.f;
            }
        }
        // 40 independent intra-segment scans (6-deep shfl chains, fully interleaved)
#pragma unroll
        for (int d = 1; d < 64; d <<= 1) {
#pragma unroll
            for (int cri = 0; cri < 8; ++cri)
#pragma unroll
                for (int s = 0; s < 5; ++s) {
                    const float up = __shfl_up(v[cri][s], d, 64);
                    if (lane >= d) v[cri][s] += up;
                }
        }
        // combine segments via wave-uniform totals
#pragma unroll
        for (int cri = 0; cri < 8; ++cri) {
            const float t0 = __shfl(v[cri][0], 63, 64);
            const float t1 = __shfl(v[cri][1], 63, 64);
            const float t2 = __shfl(v[cri][2], 63, 64);
            const float t3 = __shfl(v[cri][3], 63, 64);
            const float o1 = t0, o2 = o1 + t1, o3 = o2 + t2, o4 = o3 + t3;
            v[cri][1] += o1; v[cri][2] += o2; v[cri][3] += o3; v[cri][4] += o4;
        }
#pragma unroll
        for (int cri = 0; cri < 8; ++cri) {
            const int cr = wv * 8 + cri;
#pragma unroll
            for (int s = 0; s < 5; ++s) {
                const int x = s * 64 + lane;
                if (x < FW) sl[cr][x] = v[cri][s];
            }
        }
        __syncthreads();
        const int cw = lane & 31, xo = lane >> 5;
        for (int xi = wv * 2; xi < FW; xi += 8) {
            const int xx = xi + xo;
            iit[(size_t)(y * FW + xx) * FC + cb + cw] = sl[cw][xx];
        }
        return;
    }
    const int b = blockIdx.x - 768;
    const float step = 80.f / 159.f;
    if (b < 99) {
        // X tap table per p, invx folded into weights
        const int p = b * 256 + tid;
        if (p < NP) {
            const int d = p / 159, w = p - d * 159;
            const float z0 = 1.f + d * step, z1 = z0 + step;
            const float xa = -40.f + w * step, xb = xa + step;
            const float n00 = clip1((1000.f * xa + 1248.f * z0) / z0 * (2.f / 2496.f) - 1.f);
            const float n10 = clip1((1000.f * xa + 1248.f * z1) / z1 * (2.f / 2496.f) - 1.f);
            const float n01 = clip1((1000.f * xb + 1248.f * z0) / z0 * (2.f / 2496.f) - 1.f);
            const float n11 = clip1((1000.f * xb + 1248.f * z1) / z1 * (2.f / 2496.f) - 1.f);
            const float xmin = fminf(n00, n10);
            const float xmax = fmaxf(n11, n01);
            const float pa = (xmin + 1.f) * (0.5f * FW) - 0.5f;
            const float pb = (xmax + 1.f) * (0.5f * FW) - 0.5f;
            const float fa = floorf(pa), fb = floorf(pb);
            const float wa = pa - fa, wb = pb - fb;
            const int a0 = (int)fa, b0 = (int)fb;
            const float xd = xmax - xmin;
            const float invx = (xd > 0.f) ? (1.f / xd) : 0.f;
            int   cc[4] = { a0, a0 + 1, b0, b0 + 1 };
            float ww[4] = { -(1.f - wa), -wa, (1.f - wb), wb };
#pragma unroll
            for (int i = 0; i < 4; ++i) {
                if (cc[i] < 0 || cc[i] >= FW) { cc[i] = 0; ww[i] = 0.f; }
                ww[i] *= invx;
            }
            XTc[p] = make_int4(cc[0], cc[1], cc[2], cc[3]);
            XTw[p] = make_float4(ww[0], ww[1], ww[2], ww[3]);
        }
    } else if (b < 139) {
        // per-d deduplicated + group-4-padded y-row tables; one wave per d
        const int d = (b - 99) * 4 + wv;
        if (d < 159) {
            const int t = lane;
            const int kcell = (t >> 2) & 7;
            const int tap = t & 3;
            const float z0 = 1.f + d * step, z1 = z0 + step;
            const float ya = -2.f + 0.5f * kcell, yb2 = ya + 0.5f;
            const float m0 = clip1((1000.f * ya  + 384.f * z0) / z0 * (2.f / 768.f) - 1.f);
            const float m1 = clip1((1000.f * ya  + 384.f * z1) / z1 * (2.f / 768.f) - 1.f);
            const float M0 = clip1((1000.f * yb2 + 384.f * z0) / z0 * (2.f / 768.f) - 1.f);
            const float M1 = clip1((1000.f * yb2 + 384.f * z1) / z1 * (2.f / 768.f) - 1.f);
            const float ymin = fminf(m0, m1);
            const float ymax = fmaxf(M0, M1);
            const float yd = ymax - ymin;
            const float invy = (yd > 0.f) ? (1.f / (yd * (FH * FW * 0.25f))) : 0.f;
            const float pa = (ymin + 1.f) * (0.5f * FH) - 0.5f;
            const float pb = (ymax + 1.f) * (0.5f * FH) - 0.5f;
            const float fa = floorf(pa), fb = floorf(pb);
            const float wa = pa - fa, wb = pb - fb;
            int row; float w;
            if      (tap == 0) { row = (int)fa;     w = -(1.f - wa); }
            else if (tap == 1) { row = (int)fa + 1; w = -wa; }
            else if (tap == 2) { row = (int)fb;     w =  (1.f - wb); }
            else               { row = (int)fb + 1; w =  wb; }
            w *= invy;
            const bool valid = (t < 28) && (row >= 0) && (row < FH) && (w != 0.f);
            if (!valid) { row = 0; w = 0.f; }
            int first = 63;
#pragma unroll
            for (int j = 0; j < 28; ++j) {
                const int rj = __shfl(row, j, 64);
                if (rj == row && j < first) first = j;
            }
            const bool leader = (t < 28) && (first == t);
            const unsigned long long mask = __ballot(leader);
            const int slot = (int)__popcll(mask & ((1ull << t) - 1ull));
            const int Rn = (int)__popcll(mask);
            const int ng = (Rn + 3) >> 2;
            float s0 = 0.f, s1 = 0.f, s2 = 0.f, s3 = 0.f, s4 = 0.f, s5 = 0.f, s6 = 0.f;
#pragma unroll
            for (int j = 0; j < 28; ++j) {
                const int rj = __shfl(row, j, 64);
                const float wj = __shfl(w, j, 64);
                const float add = (rj == row) ? wj : 0.f;
                const int kj = j >> 2;
                if      (kj == 0) s0 += add;
                else if (kj == 1) s1 += add;
                else if (kj == 2) s2 += add;
                else if (kj == 3) s3 += add;
                else if (kj == 4) s4 += add;
                else if (kj == 5) s5 += add;
                else              s6 += add;
            }
            if (leader) {
                float* rec = YRt + ((size_t)d * 28 + slot) * 8;
                rec[0] = s0; rec[1] = s1; rec[2] = s2; rec[3] = s3;
                rec[4] = s4; rec[5] = s5; rec[6] = s6;
                ((int*)rec)[7] = 0;  // row written below as int
                ((int*)rec)[7] = row;
            }
            if ((t >= Rn) && (t < ng * 4)) {           // zero-pad to full groups
                float* rec = YRt + ((size_t)d * 28 + t) * 8;
                rec[0] = 0.f; rec[1] = 0.f; rec[2] = 0.f; rec[3] = 0.f;
                rec[4] = 0.f; rec[5] = 0.f; rec[6] = 0.f;
                ((int*)rec)[7] = 0;
            }
            if (t == 0) Rd[d] = ng;
        }
    } else if (b < 144) {
        // fallback per-(d,kc) y tables (folded weights) — only used on the C path
        const int p = (b - 139) * 256 + tid;
        if (p < 159 * NCELL) {
            const int d = p / NCELL, k = p - (p / NCELL) * NCELL;
            const float z0 = 1.f + d * step, z1 = z0 + step;
            const float ya = -2.f + 0.5f * k, yb2 = ya + 0.5f;
            const float m0 = clip1((1000.f * ya  + 384.f * z0) / z0 * (2.f / 768.f) - 1.f);
            const float m1 = clip1((1000.f * ya  + 384.f * z1) / z1 * (2.f / 768.f) - 1.f);
            const float M0 = clip1((1000.f * yb2 + 384.f * z0) / z0 * (2.f / 768.f) - 1.f);
            const float M1 = clip1((1000.f * yb2 + 384.f * z1) / z1 * (2.f / 768.f) - 1.f);
            const float ymin = fminf(m0, m1);
            const float ymax = fmaxf(M0, M1);
            const float yd = ymax - ymin;
            const float invy = (yd > 0.f) ? (1.f / (yd * (FH * FW * 0.25f))) : 0.f;
            const float pa = (ymin + 1.f) * (0.5f * FH) - 0.5f;
            const float pb = (ymax + 1.f) * (0.5f * FH) - 0.5f;
            const float fa = floorf(pa), fb = floorf(pb);
            const float wa = pa - fa, wb = pb - fb;
            const int a0 = (int)fa, b0 = (int)fb;
            int   rr[4] = { a0, a0 + 1, b0, b0 + 1 };
            float rw[4] = { -(1.f - wa), -wa, (1.f - wb), wb };
#pragma unroll
            for (int i = 0; i < 4; ++i) {
                if (rr[i] < 0 || rr[i] >= FH) { rr[i] = 0; rw[i] = 0.f; }
                rw[i] *= invy;
            }
            YTc[p] = make_int4(rr[0], rr[1], rr[2], rr[3]);
            YTw[p] = make_float4(rw[0], rw[1], rw[2], rw[3]);
        }
    } else {
        // LDS-staged B2 repack (sw overlays sl). Block -> (ks, nt).
        float (*sw)[224] = (float(*)[224])&sl[0][0];
        const int bb = b - 144;               // 0..127
        const int ks = bb >> 4, nt2 = bb & 15;
        for (int idx = tid; idx < 3584; idx += 256) {
            const int n = idx / 224, off = idx - n * 224;
            sw[n][off] = W[(size_t)(nt2 * 16 + n) * KDIM + ks * 224 + off];
        }
        __syncthreads();
        for (int ee = tid; ee < 3584; ee += 256) {
            const int kc = ee >> 9, ln = (ee >> 3) & 63, j = ee & 7;
            const int nl = ln & 15, cl = ((ln >> 4) & 3) * 8 + j;
            B2[(size_t)kc * 65536 + ks * 8192 + nt2 * 512 + ln * 8 + j] = f2bf(sw[nl][cl * 7 + kc]);
        }
    }
}

// ---------------- K1b: y-cumsum, y split into FOUR 24-row quarters ----------------
// R15 closed the budget: ysum ~25-28us vs 9.7us BW floor -> latency/TLP-bound
// (2.4 waves/SIMD, 48-deep serial scan). 512 threads: quarter totals via LDS,
// prefix after one barrier. Waves 2x (4.9/SIMD), chain and reg-array halved.
__global__ __launch_bounds__(512) void k_ysum(float* __restrict__ iit) {
    __shared__ float tot[3][128];
    const int x = blockIdx.x;
    const int cl = threadIdx.x & 127;
    const int qf = threadIdx.x >> 7;        // 0..3 y-quarter
    const int c = blockIdx.y * 128 + cl;
    float* base = iit + (size_t)x * FC + c + (size_t)(qf * 24) * (FW * FC);
    float v[24];
#pragma unroll
    for (int y = 0; y < 24; ++y) v[y] = base[(size_t)y * (FW * FC)];
    float s = 0.f;
#pragma unroll
    for (int y = 0; y < 24; ++y) { s += v[y]; v[y] = s; }
    if (qf < 3) tot[qf][cl] = s;
    __syncthreads();
    float off = 0.f;
    if (qf > 0) off += tot[0][cl];
    if (qf > 1) off += tot[1][cl];
    if (qf > 2) off += tot[2][cl];
#pragma unroll
    for (int y = 0; y < 24; ++y) base[(size_t)y * (FW * FC)] = v[y] + off;
}

// ---------------- K3a: dedup gather -> vox[p][kc*256+c] (bf16), one wave per p ----------------
// Frozen config (84us, memory-bound): SINGLE dispatch (R15 split cost +15us from lost
// L2 reuse), 256t, depth-balanced strips, SALU addressing, unroll 2, packed f32x2 math.
__global__ __launch_bounds__(256, 4) void k_gather(
    const float* __restrict__ iit,
    const int4* __restrict__ XTc, const float4* __restrict__ XTw,
    const float* __restrict__ YRt, const int* __restrict__ Rd,
    unsigned short* __restrict__ vox)
{
    const int tid = threadIdx.x, lane = tid & 63, wv = tid >> 6;
    const int b = blockIdx.x;
    const int i  = b >> 3;                      // 0..791 per XCD
    const int strip = (b & 7) + (i / 99) * 8;   // 64 strips of 99 L-groups
    const int L = strip * 99 + (i % 99);
    const int p = L * 4 + wv;
    if (p >= NP) return;                       // wave-uniform
    const int4  xc = XTc[p];
    const float4 xw = XTw[p];
    const int dd = p / 159;
    const int ng = rfl(Rd[dd]);
    const float* yt = YRt + (size_t)dd * 224;
    // lane j (<28) holds the dedup'd row index of slot j for this depth
    int rowv = 0;
    if (lane < 28) rowv = ((const int*)yt)[lane * 8 + 7];
    const int c0 = rfl(xc.x), c1 = rfl(xc.y), c2 = rfl(xc.z), c3 = rfl(xc.w);
    const float wx0 = rflf(xw.x), wx1 = rflf(xw.y), wx2 = rflf(xw.z), wx3 = rflf(xw.w);
    const int lo = lane * 4;                    // shared per-lane offset (floats)
    const int u0 = c0 * FC, u1 = c1 * FC, u2 = c2 * FC, u3 = c3 * FC;  // uniform col offsets

    floatx2 a0a = {0.f,0.f}, a0b = a0a, a1a = a0a, a1b = a0a, a2a = a0a, a2b = a0a,
            a3a = a0a, a3b = a0a, a4a = a0a, a4b = a0a, a5a = a0a, a5b = a0a,
            a6a = a0a, a6b = a0a;

#define LO2(T) ((floatx2){T.x, T.y})
#define HI2(T) ((floatx2){T.z, T.w})

#pragma unroll 2
    for (int g = 0; g < ng; ++g) {
        // rows via readlane -> SGPR; all address math below is wave-uniform (SALU)
        const int r0 = __builtin_amdgcn_readlane(rowv, 4 * g + 0);
        const int r1 = __builtin_amdgcn_readlane(rowv, 4 * g + 1);
        const int r2 = __builtin_amdgcn_readlane(rowv, 4 * g + 2);
        const int r3 = __builtin_amdgcn_readlane(rowv, 4 * g + 3);
        const float* R0 = iit + (size_t)(r0 * (FW * FC));
        const float* R1 = iit + (size_t)(r1 * (FW * FC));
        const float* R2 = iit + (size_t)(r2 * (FW * FC));
        const float* R3 = iit + (size_t)(r3 * (FW * FC));
        const float* B00 = R0 + u0; const float* B01 = R0 + u1; const float* B02 = R0 + u2; const float* B03 = R0 + u3;
        const float* B10 = R1 + u0; const float* B11 = R1 + u1; const float* B12 = R1 + u2; const float* B13 = R1 + u3;
        const float* B20 = R2 + u0; const float* B21 = R2 + u1; const float* B22 = R2 + u2; const float* B23 = R2 + u3;
        const float* B30 = R3 + u0; const float* B31 = R3 + u1; const float* B32 = R3 + u2; const float* B33 = R3 + u3;
        const float4 t00 = *(const float4*)(B00 + lo);
        const float4 t01 = *(const float4*)(B01 + lo);
        const float4 t02 = *(const float4*)(B02 + lo);
        const float4 t03 = *(const float4*)(B03 + lo);
        const float4 t10 = *(const float4*)(B10 + lo);
        const float4 t11 = *(const float4*)(B11 + lo);
        const float4 t12 = *(const float4*)(B12 + lo);
        const float4 t13 = *(const float4*)(B13 + lo);
        const float4 t20 = *(const float4*)(B20 + lo);
        const float4 t21 = *(const float4*)(B21 + lo);
        const float4 t22 = *(const float4*)(B22 + lo);
        const float4 t23 = *(const float4*)(B23 + lo);
        const float4 t30 = *(const float4*)(B30 + lo);
        const float4 t31 = *(const float4*)(B31 + lo);
        const float4 t32 = *(const float4*)(B32 + lo);
        const float4 t33 = *(const float4*)(B33 + lo);
        const float* tp = yt + g * 32;
        const float4 wa0 = *(const float4*)(tp +  0), wb0 = *(const float4*)(tp +  4);
        const float4 wa1 = *(const float4*)(tp +  8), wb1 = *(const float4*)(tp + 12);
        const float4 wa2 = *(const float4*)(tp + 16), wb2 = *(const float4*)(tp + 20);
        const float4 wa3 = *(const float4*)(tp + 24), wb3 = *(const float4*)(tp + 28);
        // x-combine on packed float2 halves (v_pk_fma_f32)
        const floatx2 U0a = LO2(t00)*wx0 + LO2(t01)*wx1 + LO2(t02)*wx2 + LO2(t03)*wx3;
        const floatx2 U0b = HI2(t00)*wx0 + HI2(t01)*wx1 + HI2(t02)*wx2 + HI2(t03)*wx3;
        const floatx2 U1a = LO2(t10)*wx0 + LO2(t11)*wx1 + LO2(t12)*wx2 + LO2(t13)*wx3;
        const floatx2 U1b = HI2(t10)*wx0 + HI2(t11)*wx1 + HI2(t12)*wx2 + HI2(t13)*wx3;
        const floatx2 U2a = LO2(t20)*wx0 + LO2(t21)*wx1 + LO2(t22)*wx2 + LO2(t23)*wx3;
        const floatx2 U2b = HI2(t20)*wx0 + HI2(t21)*wx1 + HI2(t22)*wx2 + HI2(t23)*wx3;
        const floatx2 U3a = LO2(t30)*wx0 + LO2(t31)*wx1 + LO2(t32)*wx2 + LO2(t33)*wx3;
        const floatx2 U3b = HI2(t30)*wx0 + HI2(t31)*wx1 + HI2(t32)*wx2 + HI2(t33)*wx3;
        // y-accumulate per cell, packed
#define SC2(Aa, Ab, W0, W1, W2, W3) { \
        Aa += U0a*(W0) + U1a*(W1) + U2a*(W2) + U3a*(W3); \
        Ab += U0b*(W0) + U1b*(W1) + U2b*(W2) + U3b*(W3); }
        SC2(a0a, a0b, wa0.x, wa1.x, wa2.x, wa3.x)
        SC2(a1a, a1b, wa0.y, wa1.y, wa2.y, wa3.y)
        SC2(a2a, a2b, wa0.z, wa1.z, wa2.z, wa3.z)
        SC2(a3a, a3b, wa0.w, wa1.w, wa2.w, wa3.w)
        SC2(a4a, a4b, wb0.x, wb1.x, wb2.x, wb3.x)
        SC2(a5a, a5b, wb0.y, wb1.y, wb2.y, wb3.y)
        SC2(a6a, a6b, wb0.z, wb1.z, wb2.z, wb3.z)
#undef SC2
    }
#undef LO2
#undef HI2

    unsigned short* vp = vox + (size_t)p * KDIM;
#define PK2(Aa, Ab) make_uint2((unsigned)f2bf(Aa.x) | ((unsigned)f2bf(Aa.y) << 16), \
                               (unsigned)f2bf(Ab.x) | ((unsigned)f2bf(Ab.y) << 16))
    *(uint2*)(vp + 0 * 256 + lo) = PK2(a0a, a0b);
    *(uint2*)(vp + 1 * 256 + lo) = PK2(a1a, a1b);
    *(uint2*)(vp + 2 * 256 + lo) = PK2(a2a, a2b);
    *(uint2*)(vp + 3 * 256 + lo) = PK2(a3a, a3b);
    *(uint2*)(vp + 4 * 256 + lo) = PK2(a4a, a4b);
    *(uint2*)(vp + 5 * 256 + lo) = PK2(a5a, a5b);
    *(uint2*)(vp + 6 * 256 + lo) = PK2(a6a, a6b);
#undef PK2
}

// ---------------- K3b: GEMM vox(bf16) x B2 -> out, M-tile 64, 8 waves (R11 config, best) ----------------
__global__ __launch_bounds__(512, 4) void k_mm(
    const unsigned short* __restrict__ vox, const unsigned short* __restrict__ B2,
    const float* __restrict__ bias, float* __restrict__ out)
{
    __shared__ unsigned short As[64][268];
    const int tid = threadIdx.x, lane = tid & 63, wv = tid >> 6;  // wv 0..7
    const int b = blockIdx.x;
    const int L = (b & 7) * 50 + (b >> 3);   // 400 = 8 x 50
    const int p0 = L * 64;
    const int q = lane >> 4, r = lane & 15;

    floatx4 acc[4][2];
#pragma unroll
    for (int mt = 0; mt < 4; ++mt)
#pragma unroll
        for (int nt = 0; nt < 2; ++nt) acc[mt][nt] = (floatx4){0.f, 0.f, 0.f, 0.f};

    const int srow = tid >> 5, scol = (tid & 31) * 8;  // srow 0..15
    for (int kk = 0; kk < 7; ++kk) {
        // stage 64 x 256 bf16 chunk of vox (512 threads: 4 rows of 16)
#pragma unroll
        for (int r8 = 0; r8 < 4; ++r8) {
            const int row = r8 * 16 + srow;
            int pg = p0 + row; if (pg > NPR - 1) pg = NPR - 1;
            const float4 v = *(const float4*)(vox + (size_t)pg * KDIM + kk * 256 + scol);
            *(float4*)&As[row][scol] = v;
        }
        __syncthreads();
#pragma unroll
        for (int ks = 0; ks < 8; ++ks) {
            short8 af[4], bf[2];
#pragma unroll
            for (int mt = 0; mt < 4; ++mt)
                af[mt] = *(const short8*)&As[mt * 16 + r][ks * 32 + q * 8];
#pragma unroll
            for (int nt = 0; nt < 2; ++nt)
                bf[nt] = *(const short8*)(B2 + (size_t)((((kk * 8 + ks) * 16) + (wv * 2 + nt)) * 64 + lane) * 8);
#pragma unroll
            for (int mt = 0; mt < 4; ++mt)
#pragma unroll
                for (int nt = 0; nt < 2; ++nt)
                    acc[mt][nt] = __builtin_amdgcn_mfma_f32_16x16x32_bf16(af[mt], bf[nt], acc[mt][nt], 0, 0, 0);
        }
        __syncthreads();
    }

#pragma unroll
    for (int nt = 0; nt < 2; ++nt) {
        const int co = wv * 32 + nt * 16 + r;
        const float bs = bias[co];
#pragma unroll
        for (int mt = 0; mt < 4; ++mt) {
            const int pb = p0 + mt * 16 + q * 4;
            float* op = out + (size_t)co * NP + pb;
            if (pb + 4 <= NP) {
                f4u vv;
                vv.x = fmaxf(acc[mt][nt][0] + bs, 0.f);
                vv.y = fmaxf(acc[mt][nt][1] + bs, 0.f);
                vv.z = fmaxf(acc[mt][nt][2] + bs, 0.f);
                vv.w = fmaxf(acc[mt][nt][3] + bs, 0.f);
                *(f4u*)op = vv;
            } else {
#pragma unroll
                for (int e2 = 0; e2 < 4; ++e2)
                    if (pb + e2 < NP) op[e2] = fmaxf(acc[mt][nt][e2] + bs, 0.f);
            }
        }
    }
}

// ---------------- fallback fused kernel (R4 lineage, folded weights) ----------------
__device__ __forceinline__ float4 gather_row_fb(
    const float* __restrict__ iit, int lane,
    const int4* __restrict__ XTc, const float4* __restrict__ XTw,
    const int4* __restrict__ YTc, const float4* __restrict__ YTw,
    int p, int kc)
{
    const int pl = (p < NP) ? p : (NP - 1);
    const int4  xc = XTc[pl];
    const float4 xw = XTw[pl];
    const int dd = (int)((unsigned)pl / 159u);
    const int4  yc = YTc[dd * NCELL + kc];
    const float4 yw = YTw[dd * NCELL + kc];
    const int r0 = rfl(yc.x), r1 = rfl(yc.y), r2 = rfl(yc.z), r3 = rfl(yc.w);
    const int c0 = rfl(xc.x), c1 = rfl(xc.y), c2 = rfl(xc.z), c3 = rfl(xc.w);
    const float keep = (p < NP) ? 1.f : 0.f;
    const float wy0 = rflf(yw.x) * keep, wy1 = rflf(yw.y) * keep, wy2 = rflf(yw.z) * keep, wy3 = rflf(yw.w) * keep;
    const float wx0 = rflf(xw.x), wx1 = rflf(xw.y), wx2 = rflf(xw.z), wx3 = rflf(xw.w);
    const int lo = lane * 4;
    const float* q00 = iit + (size_t)(r0 * FW + c0) * FC + lo;
    const float* q01 = iit + (size_t)(r0 * FW + c1) * FC + lo;
    const float* q02 = iit + (size_t)(r0 * FW + c2) * FC + lo;
    const float* q03 = iit + (size_t)(r0 * FW + c3) * FC + lo;
    const float* q10 = iit + (size_t)(r1 * FW + c0) * FC + lo;
    const float* q11 = iit + (size_t)(r1 * FW + c1) * FC + lo;
    const float* q12 = iit + (size_t)(r1 * FW + c2) * FC + lo;
    const float* q13 = iit + (size_t)(r1 * FW + c3) * FC + lo;
    const float* q20 = iit + (size_t)(r2 * FW + c0) * FC + lo;
    const float* q21 = iit + (size_t)(r2 * FW + c1) * FC + lo;
    const float* q22 = iit + (size_t)(r2 * FW + c2) * FC + lo;
    const float* q23 = iit + (size_t)(r2 * FW + c3) * FC + lo;
    const float* q30 = iit + (size_t)(r3 * FW + c0) * FC + lo;
    const float* q31 = iit + (size_t)(r3 * FW + c1) * FC + lo;
    const float* q32 = iit + (size_t)(r3 * FW + c2) * FC + lo;
    const float* q33 = iit + (size_t)(r3 * FW + c3) * FC + lo;
    const float4 t00 = *(const float4*)q00;
    const float4 t01 = *(const float4*)q01;
    const float4 t02 = *(const float4*)q02;
    const float4 t03 = *(const float4*)q03;
    const float4 t10 = *(const float4*)q10;
    const float4 t11 = *(const float4*)q11;
    const float4 t12 = *(const float4*)q12;
    const float4 t13 = *(const float4*)q13;
    const float4 t20 = *(const float4*)q20;
    const float4 t21 = *(const float4*)q21;
    const float4 t22 = *(const float4*)q22;
    const float4 t23 = *(const float4*)q23;
    const float4 t30 = *(const float4*)q30;
    const float4 t31 = *(const float4*)q31;
    const float4 t32 = *(const float4*)q32;
    const float4 t33 = *(const float4*)q33;
    float4 a = make_float4(0.f, 0.f, 0.f, 0.f);
#define ACC(T, WY, WX) { const float wt = (WY) * (WX); \
        a.x += wt * T.x; a.y += wt * T.y; a.z += wt * T.z; a.w += wt * T.w; }
    ACC(t00, wy0, wx0) ACC(t01, wy0, wx1) ACC(t02, wy0, wx2) ACC(t03, wy0, wx3)
    ACC(t10, wy1, wx0) ACC(t11, wy1, wx1) ACC(t12, wy1, wx2) ACC(t13, wy1, wx3)
    ACC(t20, wy2, wx0) ACC(t21, wy2, wx1) ACC(t22, wy2, wx2) ACC(t23, wy2, wx3)
    ACC(t30, wy3, wx0) ACC(t31, wy3, wx1) ACC(t32, wy3, wx2) ACC(t33, wy3, wx3)
#undef ACC
    return a;
}

__global__ __launch_bounds__(256, 4) void k_fusedC(
    const float* __restrict__ iit, const unsigned short* __restrict__ B2,
    const int4* __restrict__ XTc, const float4* __restrict__ XTw,
    const int4* __restrict__ YTc, const float4* __restrict__ YTw,
    const float* __restrict__ bias, float* __restrict__ out)
{
    __shared__ unsigned short As[32][264];
    const int tid = threadIdx.x, lane = tid & 63, wv = tid >> 6;
    const int b = blockIdx.x;
    const int L = (b & 7) * 99 + (b >> 3);
    const int p0 = L * 32;
    const int q = lane >> 4, r = lane & 15;

    floatx4 acc[2][4];
#pragma unroll
    for (int mt = 0; mt < 2; ++mt)
#pragma unroll
        for (int nt = 0; nt < 4; ++nt) acc[mt][nt] = (floatx4){0.f, 0.f, 0.f, 0.f};

    for (int kc = 0; kc < NCELL; ++kc) {
#pragma unroll 1
        for (int i = 0; i < 8; ++i) {
            const int pr = wv * 8 + i;
            const float4 a = gather_row_fb(iit, lane, XTc, XTw, YTc, YTw, p0 + pr, kc);
            *(uint2*)&As[pr][lane * 4] = make_uint2(
                (unsigned)f2bf(a.x) | ((unsigned)f2bf(a.y) << 16),
                (unsigned)f2bf(a.z) | ((unsigned)f2bf(a.w) << 16));
        }
        __syncthreads();
#pragma unroll
        for (int ks = 0; ks < 8; ++ks) {
            short8 af[2], bf[4];
#pragma unroll
            for (int mt = 0; mt < 2; ++mt)
                af[mt] = *(const short8*)&As[mt * 16 + r][ks * 32 + q * 8];
#pragma unroll
            for (int nt = 0; nt < 4; ++nt)
                bf[nt] = *(const short8*)(B2 + (size_t)((((kc * 8 + ks) * 16) + (wv * 4 + nt)) * 64 + lane) * 8);
#pragma unroll
            for (int mt = 0; mt < 2; ++mt)
#pragma unroll
                for (int nt = 0; nt < 4; ++nt)
                    acc[mt][nt] = __builtin_amdgcn_mfma_f32_16x16x32_bf16(af[mt], bf[nt], acc[mt][nt], 0, 0, 0);
        }
        __syncthreads();
    }

#pragma unroll
    for (int nt = 0; nt < 4; ++nt) {
        const int co = wv * 64 + nt * 16 + r;
        const float bs = bias[co];
#pragma unroll
        for (int mt = 0; mt < 2; ++mt) {
            const int pb = p0 + mt * 16 + q * 4;
            float* op = out + (size_t)co * NP + pb;
            if (pb + 4 <= NP) {
                f4u vv;
                vv.x = fmaxf(acc[mt][nt][0] + bs, 0.f);
                vv.y = fmaxf(acc[mt][nt][1] + bs, 0.f);
                vv.z = fmaxf(acc[mt][nt][2] + bs, 0.f);
                vv.w = fmaxf(acc[mt][nt][3] + bs, 0.f);
                *(f4u*)op = vv;
            } else {
#pragma unroll
                for (int e2 = 0; e2 < 4; ++e2)
                    if (pb + e2 < NP) op[e2] = fmaxf(acc[mt][nt][e2] + bs, 0.f);
            }
        }
    }
}

// ---------------- launch ----------------
extern "C" void kernel_launch(void* const* d_in, const int* in_sizes, int n_in,
                              void* d_out, int out_size, void* d_ws, size_t ws_size,
                              hipStream_t stream) {
    (void)in_sizes; (void)n_in; (void)out_size;
    const float* features = (const float*)d_in[0];
    const float* W_lin    = (const float*)d_in[4];
    const float* b_lin    = (const float*)d_in[5];
    float* out = (float*)d_out;
    char* ws = (char*)d_ws;

    float*          iit = (float*)(ws + 0);                 // 30,670,848
    unsigned short* B2  = (unsigned short*)(ws + 30670848); //    917,504 -> 31,588,352
    int4*   XTc = (int4*)  (ws + 31588352);                 //    405,504 -> 31,993,856
    float4* XTw = (float4*)(ws + 31993856);                 //    405,504 -> 32,399,360
    float*  YRt = (float*) (ws + 32399360);                 //    142,464 -> 32,541,824
    int*    Rd  = (int*)   (ws + 32541824);                 //        640 -> 32,542,464
    int4*   YTc = (int4*)  (ws + 32542464);                 //     17,920 -> 32,560,384
    float4* YTw = (float4*)(ws + 32560384);                 //     17,920 -> 32,578,304
    unsigned short* vox = (unsigned short*)(ws + 32578304); // 90,832,896 -> 123,411,200

    k_xscanT<<<1040, 256, 0, stream>>>(features, iit, W_lin, B2, XTc, XTw, YRt, Rd, YTc, YTw);
    k_ysum  <<<dim3(312, 2), 512, 0, stream>>>(iit);

    if (ws_size >= 123411200ull) {
        k_gather<<<6336, 256, 0, stream>>>(iit, XTc, XTw, YRt, Rd, vox);
        k_mm    <<<400, 512, 0, stream>>>(vox, B2, b_lin, out);
    } else {
        k_fusedC<<<792, 256, 0, stream>>>(iit, B2, XTc, XTw, YTc, YTw, b_lin, out);
    }
}